// Round 8
// baseline (2715.397 us; speedup 1.0000x reference)
//
#include <hip/hip_runtime.h>
#include <math.h>

typedef _Float16 f16;
typedef _Float16 f16x8 __attribute__((ext_vector_type(8)));
typedef float    f32x4 __attribute__((ext_vector_type(4)));

#define MFMA16(A, B, C) __builtin_amdgcn_mfma_f32_16x16x32_f16((A), (B), (C), 0, 0, 0)
#define LOG2E 1.44269504088896f

// Weights/biases pre-scaled by -log2e (sigmoid) or -2*log2e (g gate):
// sigma(z) = rcp(1 + 2^acc) with a bare v_exp_f32.
__device__ __forceinline__ float sig2(float a) {
    return __builtin_amdgcn_rcpf(1.0f + __builtin_amdgcn_exp2f(a));
}
__device__ __forceinline__ float tanh2(float c) {
    return fmaf(2.0f, sig2(c * (-2.0f * LOG2E)), -1.0f);
}

__device__ __forceinline__ f16x8 ldfrag(const float* __restrict__ W, int n, int k0, float s) {
    const float* p = W + (size_t)n * 64 + k0;
    f16x8 r;
#pragma unroll
    for (int j = 0; j < 8; j++) r[j] = (f16)(s * p[j]);
    return r;
}

#define SMEM_BYTES 92160

// One block per BATCH PAIR; 512 threads = 8 waves, layer-specialized:
// waves 0-3 ("A") = encoder L1 / decoder dec1; waves 4-7 ("B") = encoder L2 /
// decoder dec2. Identical to the 830us round-6 kernel EXCEPT one change:
//
// ROUND-8: L2's input projection E2ih@h1 is TIME-BATCHED on B: 8 ticks x 2
// batches fill the 16 MFMA M-rows (row = bat*8 + tickoff), so an 8-tick proj
// window costs 8 MFMAs total (1/tick amortized) instead of 8/tick. Per-SIMD
// encoder MFMA load drops 24 -> 17. L2 lags L1 by 16 ticks: window w (ticks
// 8w..8w+7) is read at interval 8w+8 (h1 complete, barrier-ordered),
// computed 1 MFMA/interval over [8w+8, 8w+15], consumed from 8w+16.
// Each B-wave projects its OWN 16 units -> no new cross-wave edges.
// h1l is a 16-deep ring with the SAME 128B row stride as the proven kernels.
// Everything else (syncthreads, f32 LDS staging, decoder) is round-6 verbatim.
__global__ __launch_bounds__(512, 1)
void seq2seq_kernel(const float* __restrict__ src, const float* __restrict__ trg,
                    const float* __restrict__ e1ih, const float* __restrict__ e1hh,
                    const float* __restrict__ e1b,
                    const float* __restrict__ e2ih, const float* __restrict__ e2hh,
                    const float* __restrict__ e2b,
                    const float* __restrict__ d1ih, const float* __restrict__ d1hh,
                    const float* __restrict__ d1b,
                    const float* __restrict__ d2ih, const float* __restrict__ d2hh,
                    const float* __restrict__ d2b,
                    const float* __restrict__ fcW, const float* __restrict__ fcb,
                    float* __restrict__ out)
{
    extern __shared__ __align__(16) char smem[];
    float* xst   = (float*)smem;                 // [1024][8] src, 32 KB
    float* tst   = (float*)(smem + 32768);       // [512][8] trg, 16 KB
    f16*   h1lp  = (f16*)(smem + 49152);         // [16][2][64] h1 ring, 4 KB
    f16*   h2lp  = (f16*)(smem + 53248);         // [2][2][64]
    float* c1buf = (float*)(smem + 53760);       // [2][64] dec1 cell out (A->B)
    float* c2buf = (float*)(smem + 54272);       // [2][64] dec2 cell out (B->A)
    f16*   ringp = (f16*)(smem + 54784);         // [2][16][72] h2 history, 4.5 KB
    float* prjp  = (float*)(smem + 59392);       // [16][2][64][4] proj ring, 32 KB

    const int bp   = blockIdx.x;
    const int tid  = threadIdx.x;
    const int wv   = tid >> 6;               // 0..7
    const bool isB = (wv >= 4);
    const int wvg  = wv & 3;
    const int lane = tid & 63;
    const int quad = lane >> 4;
    const int c15  = lane & 15;
    const int u16  = wvg * 16 + c15;
    const int qb   = quad & 1;               // batch this lane's activations
    const int ab   = c15 & 1;                // batch this lane's A-row feeds

    // ---- one-time staging of src/trg into LDS (f32, round-6 verbatim) ----
    {
        const float* s0 = src + (size_t)(2 * bp) * 3072;
        const float* s1 = s0 + 3072;
        for (int i = tid; i < 3072; i += 512) {
            int t = i / 3, c = i - 3 * t;
            xst[t * 8 + c]     = s0[i];
            xst[t * 8 + 4 + c] = s1[i];
        }
        const float* t0p = trg + (size_t)(2 * bp) * 1536;
        const float* t1p = t0p + 1536;
        for (int i = tid; i < 1536; i += 512) {
            int t = i / 3, c = i - 3 * t;
            tst[t * 8 + c]     = t0p[i];
            tst[t * 8 + 4 + c] = t1p[i];
        }
    }

    // ---- group-specialized encoder weights ----
    f16x8 E1hh[4][2];                        // A: L1 hh
    f16x8 Wi0[4], Wi1[4], Wh0[4], Wh1[4];    // B: L2 ih (proj) + hh
    float xw[4][3], bias1[4];
    f32x4 bs2[4];                            // B: bias2 splat (MFMA C-init)
    if (!isB) {
#pragma unroll
        for (int g = 0; g < 4; g++) {
            const float s = (g == 2) ? (-2.0f * LOG2E) : (-LOG2E);
            const int n = g * 64 + u16;
            E1hh[g][0] = ldfrag(e1hh, n, quad * 8, s);
            E1hh[g][1] = ldfrag(e1hh, n, 32 + quad * 8, s);
            xw[g][0] = s * e1ih[n * 3 + 0];
            xw[g][1] = s * e1ih[n * 3 + 1];
            xw[g][2] = s * e1ih[n * 3 + 2];
            bias1[g] = s * e1b[n];
        }
    } else {
#pragma unroll
        for (int g = 0; g < 4; g++) {
            const float s = (g == 2) ? (-2.0f * LOG2E) : (-LOG2E);
            const int n = g * 64 + u16;
            Wi0[g] = ldfrag(e2ih, n, quad * 8, s);
            Wi1[g] = ldfrag(e2ih, n, 32 + quad * 8, s);
            Wh0[g] = ldfrag(e2hh, n, quad * 8, s);
            Wh1[g] = ldfrag(e2hh, n, 32 + quad * 8, s);
            float bv = s * e2b[n];
            bs2[g] = (f32x4){bv, bv, bv, bv};
        }
    }

    float c1 = 0.f, c2 = 0.f;                // c1 lives in A, c2 in B
    for (int i = tid; i < 2048; i += 512) h1lp[i] = (f16)0.f;   // all ring slots
    if (tid < 256) h2lp[tid] = (f16)0.f;
    __syncthreads();

    const f32x4 z4 = {0.f, 0.f, 0.f, 0.f};

    // x prefetch registers (A only)
    f32x4 xq = z4, xnq = z4;
    if (!isB) xq = *(const f32x4*)&xst[0 + qb * 4];

    // B: proj-window state carried across intervals in registers
    f16x8 pa0 = {}, pa1 = {};
    f32x4 pacc = z4;

    // ---------------- encoder: 1040 pipelined ticks, 1 barrier each --------
    // tick tau: A computes h1(tau) [tau<1024]; B computes h2(tau-16)
    // [tau>=16] plus one proj-window MFMA [8<=tau<1032].
#pragma unroll 1
    for (int tau = 0; tau < 1040; tau++) {
        if (!isB) {
            if (tau < 1024) {                // L1: h1(tau) = f(h1(tau-1), x(tau))
                const f16* h1p = h1lp + ((tau + 15) & 15) * 128 + ab * 64;
                f16x8 a0 = *(const f16x8*)(h1p + quad * 8);
                f16x8 a1 = *(const f16x8*)(h1p + 32 + quad * 8);
                float xt[4];
#pragma unroll
                for (int g = 0; g < 4; g++)
                    xt[g] = fmaf(xw[g][0], xq.x,
                            fmaf(xw[g][1], xq.y, fmaf(xw[g][2], xq.z, bias1[g])));
                f32x4 acc[4];
#pragma unroll
                for (int g = 0; g < 4; g++)
                    acc[g] = MFMA16(a1, E1hh[g][1], MFMA16(a0, E1hh[g][0], z4));
                float v[4];
#pragma unroll
                for (int g = 0; g < 4; g++)
                    v[g] = (qb ? acc[g][1] : acc[g][0]) + xt[g];
                float iv = sig2(v[0]), fv = sig2(v[1]);
                float gv = fmaf(2.0f, sig2(v[2]), -1.0f), ov = sig2(v[3]);
                c1 = fv * c1 + iv * gv;
                if (quad < 2)
                    h1lp[(tau & 15) * 128 + quad * 64 + u16] = (f16)(ov * tanh2(c1));
                // prefetch next x (read-only region; off the post-barrier burst)
                const int tn = (tau + 1 < 1024) ? tau + 1 : 1023;
                xnq = *(const f32x4*)&xst[tn * 8 + qb * 4];
            }
        } else {
            if (tau >= 16) {                 // L2: h2(tk) = f(proj(tk), h2(tk-1))
                const int tk = tau - 16;
                const f16* h2p = h2lp + ((tk + 1) & 1) * 128 + ab * 64;  // h2(tk-1)
                f16x8 b0 = *(const f16x8*)(h2p + quad * 8);
                f16x8 b1 = *(const f16x8*)(h2p + 32 + quad * 8);
                f32x4 pj = *(const f32x4*)(prjp + ((tk & 15) * 2 + qb) * 256 + u16 * 4);
                f32x4 accB[4];               // bias via C-init
#pragma unroll
                for (int g = 0; g < 4; g++)
                    accB[g] = MFMA16(b1, Wh1[g], MFMA16(b0, Wh0[g], bs2[g]));
                float v[4];
#pragma unroll
                for (int g = 0; g < 4; g++)
                    v[g] = pj[g] + (qb ? accB[g][1] : accB[g][0]);
                float iv = sig2(v[0]), fv = sig2(v[1]);
                float gv = fmaf(2.0f, sig2(v[2]), -1.0f), ov = sig2(v[3]);
                c2 = fv * c2 + iv * gv;
                if (quad < 2)
                    h2lp[(tk & 1) * 128 + quad * 64 + u16] = (f16)(ov * tanh2(c2));
            }
            if (tau >= 8 && tau < 1032) {    // one proj-window MFMA (slack work)
                const int s = (tau - 8) & 7, w8 = (tau - 8) >> 3;
                if (s == 0) {
                    // A-frag rows: r = bat*8 + tickoff; lane row = c15.
                    const int eoff = ((w8 * 8 + (c15 & 7)) & 15) * 128
                                   + (c15 >> 3) * 64 + quad * 8;
                    pa0 = *(const f16x8*)(h1lp + eoff);
                    pa1 = *(const f16x8*)(h1lp + eoff + 32);
                }
                const int g = s >> 1;
                if ((s & 1) == 0) {
                    pacc = MFMA16(pa0, Wi0[g], z4);
                } else {
                    pacc = MFMA16(pa1, Wi1[g], pacc);
                    // C rows: row = quad*4+rr -> bat = row>>3, tickoff = row&7
#pragma unroll
                    for (int rr = 0; rr < 4; rr++) {
                        const int row = quad * 4 + rr;
                        prjp[(((w8 * 8 + (row & 7)) & 15) * 2 + (row >> 3)) * 256
                             + u16 * 4 + g] = pacc[rr];
                    }
                }
            }
        }
        __syncthreads();
        if (!isB) xq = xnq;
    }
    // h2(1023) in h2l slot 1; c2 in B registers

    // ---------------- decoder weights (group-specialized, round-6 verbatim) --
    f16x8 D1hh[4][2];                        // A
    f16x8 W2s[4][2];                         // B
    float dxw[4][3], db1[4];
    f32x4 db2s[4];                           // B: dec2 bias splat (C-init)
    if (!isB) {
#pragma unroll
        for (int g = 0; g < 4; g++) {
            const float s = (g == 2) ? (-2.0f * LOG2E) : (-LOG2E);
            const int n = g * 64 + u16;
            D1hh[g][0] = ldfrag(d1hh, n, quad * 8, s);
            D1hh[g][1] = ldfrag(d1hh, n, 32 + quad * 8, s);
            dxw[g][0] = s * d1ih[n * 3 + 0];
            dxw[g][1] = s * d1ih[n * 3 + 1];
            dxw[g][2] = s * d1ih[n * 3 + 2];
            db1[g] = s * d1b[n];
        }
    } else {
#pragma unroll
        for (int g = 0; g < 4; g++) {
            const float s = (g == 2) ? (-2.0f * LOG2E) : (-LOG2E);
            const int n = g * 64 + u16;
#pragma unroll
            for (int c = 0; c < 2; c++) {
                const int k0 = c * 32 + quad * 8;
                const float* pa = d2ih + (size_t)n * 64 + k0;
                const float* pb = d2hh + (size_t)n * 64 + k0;
                f16x8 r2;
#pragma unroll
                for (int j = 0; j < 8; j++) r2[j] = (f16)(s * (pa[j] + pb[j]));
                W2s[g][c] = r2;
            }
            float bv = s * d2b[n];
            db2s[g] = (f32x4){bv, bv, bv, bv};
        }
        // seed c2buf with encoder final c2 (A reads it at t=0)
        if (quad < 2) c2buf[quad * 64 + u16] = c2;
    }
    // FC: register B-fragments of fcW^T (waves 6-7), B[k][n]=fcW[n][k], n=c15
    f16x8 FW0 = {}, FW1 = {};
    float fb = 0.f;
    if (wv >= 6 && c15 < 3) {
#pragma unroll
        for (int j = 0; j < 8; j++) {
            FW0[j] = (f16)fcW[c15 * 64 + quad * 8 + j];
            FW1[j] = (f16)fcW[c15 * 64 + 32 + quad * 8 + j];
        }
        fb = fcb[c15];
    }
    __syncthreads();

    // trg prefetch registers (A only)
    f32x4 tq = z4, tnq = z4;
    if (!isB) tq = *(const f32x4*)&tst[0 + qb * 4];

    // ---------------- decoder: 511 steps, 2 barriers each (round-6) ---------
    // Encoder left h2(1023) in slot 1: A reads h2l[w], B writes h2l[r].
#pragma unroll 1
    for (int t = 0; t < 511; t++) {
        const int r = t & 1, w = r ^ 1;
        if (!isB) {
            // ---- dec1 (waves 0-3) ----
            const f16* hp = h2lp + w * 128 + ab * 64;   // h2d(t-1)
            f16x8 a0 = *(const f16x8*)(hp + quad * 8);
            f16x8 a1 = *(const f16x8*)(hp + 32 + quad * 8);
            float cdin = c2buf[qb * 64 + u16];
            float xt[4];
#pragma unroll
            for (int g = 0; g < 4; g++)
                xt[g] = fmaf(dxw[g][0], tq.x,
                        fmaf(dxw[g][1], tq.y, fmaf(dxw[g][2], tq.z, db1[g])));
            f32x4 acc[4];
#pragma unroll
            for (int g = 0; g < 4; g++)
                acc[g] = MFMA16(a1, D1hh[g][1], MFMA16(a0, D1hh[g][0], z4));
            float v[4];
#pragma unroll
            for (int g = 0; g < 4; g++)
                v[g] = (qb ? acc[g][1] : acc[g][0]) + xt[g];
            float iv = sig2(v[0]), fv = sig2(v[1]);
            float gv = fmaf(2.0f, sig2(v[2]), -1.0f), ov = sig2(v[3]);
            float c1d = fv * cdin + iv * gv;
            if (quad < 2) {
                h1lp[w * 128 + quad * 64 + u16] = (f16)(ov * tanh2(c1d));
                c1buf[quad * 64 + u16] = c1d;
            }
            const int tn = (t + 1 < 511) ? t + 1 : 510;
            tnq = *(const f32x4*)&tst[tn * 8 + qb * 4];
        } else if (wv >= 6 && t > 0 && (t & 15) == 0) {
            // ---- batched FC for steps t-16..t-1 (2 MFMAs), overlapped ----
            const int bsel = wv - 6;
            const f16* rp = ringp + bsel * 1152;
            f16x8 fa0 = *(const f16x8*)(rp + c15 * 72 + quad * 8);
            f16x8 fa1 = *(const f16x8*)(rp + c15 * 72 + 32 + quad * 8);
            f32x4 acc = MFMA16(fa1, FW1, MFMA16(fa0, FW0, z4));
            if (c15 < 3) {
                float* ob = out + (((size_t)(2 * bp + bsel) * 512 + (t - 15)) * 3) + c15;
#pragma unroll
                for (int rg = 0; rg < 4; rg++)
                    ob[(quad * 4 + rg) * 3] = acc[rg] + fb;
            }
        }
        __syncthreads();   // B1: h1d, c1d visible
        if (!isB) tq = tnq;

        if (isB) {
            // ---- dec2 (waves 4-7): x = h = h1d ----
            const f16* np = h1lp + w * 128 + ab * 64;
            f16x8 m0 = *(const f16x8*)(np + quad * 8);
            f16x8 m1 = *(const f16x8*)(np + 32 + quad * 8);
            float c1in = c1buf[qb * 64 + u16];
            f32x4 acc[4];
#pragma unroll
            for (int g = 0; g < 4; g++)
                acc[g] = MFMA16(m1, W2s[g][1], MFMA16(m0, W2s[g][0], db2s[g]));
            float v[4];
#pragma unroll
            for (int g = 0; g < 4; g++)
                v[g] = (qb ? acc[g][1] : acc[g][0]);
            float i2 = sig2(v[0]), f2 = sig2(v[1]);
            float g2 = fmaf(2.0f, sig2(v[2]), -1.0f), o2 = sig2(v[3]);
            float c2d = f2 * c1in + i2 * g2;
            if (quad < 2) {
                f16 hh = (f16)(o2 * tanh2(c2d));
                h2lp[r * 128 + quad * 64 + u16] = hh;
                c2buf[quad * 64 + u16] = c2d;
                ringp[quad * 1152 + (t & 15) * 72 + u16] = hh;   // FC history
            }
        }
        __syncthreads();   // B2: hD(t), c2d visible
    }

    // drain: FC for steps 496..510 (ring slots 0..14) -> out rows 497..511
    if (wv >= 6) {
        const int bsel = wv - 6;
        const f16* rp = ringp + bsel * 1152;
        f16x8 fa0 = *(const f16x8*)(rp + c15 * 72 + quad * 8);
        f16x8 fa1 = *(const f16x8*)(rp + c15 * 72 + 32 + quad * 8);
        f32x4 acc = MFMA16(fa1, FW1, MFMA16(fa0, FW0, z4));
        if (c15 < 3) {
            float* ob = out + (((size_t)(2 * bp + bsel) * 512 + 497) * 3) + c15;
#pragma unroll
            for (int rg = 0; rg < 4; rg++) {
                int step = quad * 4 + rg;
                if (step < 15) ob[step * 3] = acc[rg] + fb;
            }
        }
    }
}

extern "C" void kernel_launch(void* const* d_in, const int* in_sizes, int n_in,
                              void* d_out, int out_size, void* d_ws, size_t ws_size,
                              hipStream_t stream)
{
    const float* src   = (const float*)d_in[0];
    const float* trg   = (const float*)d_in[1];
    const float* e1ih  = (const float*)d_in[2];
    const float* e1hh  = (const float*)d_in[3];
    const float* e1b   = (const float*)d_in[4];
    const float* e2ih  = (const float*)d_in[5];
    const float* e2hh  = (const float*)d_in[6];
    const float* e2b   = (const float*)d_in[7];
    const float* dd1ih = (const float*)d_in[8];
    const float* dd1hh = (const float*)d_in[9];
    const float* dd1b  = (const float*)d_in[10];
    const float* dd2ih = (const float*)d_in[11];
    const float* dd2hh = (const float*)d_in[12];
    const float* dd2b  = (const float*)d_in[13];
    const float* fcW   = (const float*)d_in[14];
    const float* fcb   = (const float*)d_in[15];
    float* out = (float*)d_out;

    static bool attr_set = false;
    if (!attr_set) {
        hipFuncSetAttribute((const void*)seq2seq_kernel,
                            hipFuncAttributeMaxDynamicSharedMemorySize, SMEM_BYTES);
        attr_set = true;
    }

    // outputs[:, 0, :] stays 0; decoder fills t >= 1
    hipMemsetAsync(d_out, 0, (size_t)out_size * sizeof(float), stream);

    seq2seq_kernel<<<256, 512, SMEM_BYTES, stream>>>(src, trg,
                                            e1ih, e1hh, e1b, e2ih, e2hh, e2b,
                                            dd1ih, dd1hh, dd1b, dd2ih, dd2hh, dd2b,
                                            fcW, fcb, out);
}

// Round 9
// 827.560 us; speedup vs baseline: 3.2812x; 3.2812x over previous
//
#include <hip/hip_runtime.h>
#include <math.h>

typedef _Float16 f16;
typedef _Float16 f16x8 __attribute__((ext_vector_type(8)));
typedef float    f32x4 __attribute__((ext_vector_type(4)));

#define MFMA16(A, B, C) __builtin_amdgcn_mfma_f32_16x16x32_f16((A), (B), (C), 0, 0, 0)
#define LOG2E 1.44269504088896f

// Weights/biases pre-scaled by -log2e (sigmoid) or -2*log2e (g gate):
// sigma(z) = rcp(1 + 2^acc) with a bare v_exp_f32.
__device__ __forceinline__ float sig2(float a) {
    return __builtin_amdgcn_rcpf(1.0f + __builtin_amdgcn_exp2f(a));
}
__device__ __forceinline__ float tanh2(float c) {
    return fmaf(2.0f, sig2(c * (-2.0f * LOG2E)), -1.0f);
}

__device__ __forceinline__ f16x8 ldfrag(const float* __restrict__ W, int n, int k0, float s) {
    const float* p = W + (size_t)n * 64 + k0;
    f16x8 r;
#pragma unroll
    for (int j = 0; j < 8; j++) r[j] = (f16)(s * p[j]);
    return r;
}

// One block per BATCH PAIR; 512 threads = 8 waves, layer-specialized:
// waves 0-3 ("A") = encoder L1 / decoder dec1; waves 4-7 ("B") = encoder L2 /
// decoder dec2. FC head: h2 history ring (16 steps) + 2 MFMAs on waves 6-7
// every 16 steps. M=2 MFMA rows: batch = row&1 -> C reg0=batch0, reg1=batch1.
//
// Encoder L2's input projection E2ih@h1 is computed by A-waves (which already
// hold the h1(tau-1) fragments for their own hh-MFMA -- zero extra LDS reads)
// one tick AHEAD, into a double-buffered f32 pre-gate ring prj. B (computing
// h2(tau-2) at tick tau) reads one f32x4 of pre-gates instead of 8 ih-MFMAs
// + 2 ds_reads on its post-barrier critical chain.
//
// SESSION VERDICT (9 probes): this structure is a sharp local optimum at
// ~830 us. The 2047 serial intervals are bound by ~700cy/interval of
// cross-wave handoff fixed cost (barrier + post-barrier LDS latency + act
// chain), insensitive to MFMA redistribution (R6: neutral) or deletion
// (R7/R8: 3.3x REGRESSION from scheduling pathology). Alternative syncs all
// regressed: +barrier +90%, flags +56%, zero-barrier wave-specialized +136%.
// Do not restructure; the next lever, if any, is at the ISA/disasm level.
__global__ __launch_bounds__(512, 1)
void seq2seq_kernel(const float* __restrict__ src, const float* __restrict__ trg,
                    const float* __restrict__ e1ih, const float* __restrict__ e1hh,
                    const float* __restrict__ e1b,
                    const float* __restrict__ e2ih, const float* __restrict__ e2hh,
                    const float* __restrict__ e2b,
                    const float* __restrict__ d1ih, const float* __restrict__ d1hh,
                    const float* __restrict__ d1b,
                    const float* __restrict__ d2ih, const float* __restrict__ d2hh,
                    const float* __restrict__ d2b,
                    const float* __restrict__ fcW, const float* __restrict__ fcb,
                    float* __restrict__ out)
{
    const int bp   = blockIdx.x;
    const int tid  = threadIdx.x;
    const int wv   = tid >> 6;               // 0..7
    const bool isB = (wv >= 4);
    const int wvg  = wv & 3;
    const int lane = tid & 63;
    const int quad = lane >> 4;
    const int c15  = lane & 15;
    const int u16  = wvg * 16 + c15;
    const int qb   = quad & 1;               // batch this lane's activations
    const int ab   = c15 & 1;                // batch this lane's A-row feeds

    __shared__ __align__(16) float xst[1024][8];   // [t][bat*4+c] src, 32 KB
    __shared__ __align__(16) float tst[512][8];    // trg, 16 KB
    __shared__ __align__(16) f16 h1l[2][2][64];    // [buf][bat][u]
    __shared__ __align__(16) f16 h2l[2][2][64];
    __shared__ float c1buf[2][64];                 // dec1 cell out (A -> B)
    __shared__ float c2buf[2][64];                 // dec2 cell out (B -> A)
    __shared__ __align__(16) f16 ring[2][16][72];  // [bat][step&15][u] h2 history
    __shared__ __align__(16) float prj[2][2][64][4]; // L2 ih pre-gates [buf][bat][u][g], 4 KB

    // ---- one-time staging of src/trg into LDS ----
    {
        const float* s0 = src + (size_t)(2 * bp) * 3072;
        const float* s1 = s0 + 3072;
        for (int i = tid; i < 3072; i += 512) {
            int t = i / 3, c = i - 3 * t;
            xst[t][c]     = s0[i];
            xst[t][4 + c] = s1[i];
        }
        const float* t0p = trg + (size_t)(2 * bp) * 1536;
        const float* t1p = t0p + 1536;
        for (int i = tid; i < 1536; i += 512) {
            int t = i / 3, c = i - 3 * t;
            tst[t][c]     = t0p[i];
            tst[t][4 + c] = t1p[i];
        }
    }

    // ---- group-specialized encoder weights ----
    f16x8 E1hh[4][2], E2ih[4][2];            // A: own hh + L2's ih (proj producer)
    f16x8 E2hh[4][2];                        // B: hh only
    float xw[4][3], bias1[4];
    f32x4 bs2[4];                            // B: bias2 splat (MFMA C-init)
    if (!isB) {
#pragma unroll
        for (int g = 0; g < 4; g++) {
            const float s = (g == 2) ? (-2.0f * LOG2E) : (-LOG2E);
            const int n = g * 64 + u16;
#pragma unroll
            for (int c = 0; c < 2; c++) {
                E1hh[g][c] = ldfrag(e1hh, n, c * 32 + quad * 8, s);
                E2ih[g][c] = ldfrag(e2ih, n, c * 32 + quad * 8, s);
            }
            xw[g][0] = s * e1ih[n * 3 + 0];
            xw[g][1] = s * e1ih[n * 3 + 1];
            xw[g][2] = s * e1ih[n * 3 + 2];
            bias1[g] = s * e1b[n];
        }
    } else {
#pragma unroll
        for (int g = 0; g < 4; g++) {
            const float s = (g == 2) ? (-2.0f * LOG2E) : (-LOG2E);
            const int n = g * 64 + u16;
#pragma unroll
            for (int c = 0; c < 2; c++)
                E2hh[g][c] = ldfrag(e2hh, n, c * 32 + quad * 8, s);
            float bv = s * e2b[n];
            bs2[g] = (f32x4){bv, bv, bv, bv};
        }
    }

    float c1 = 0.f, c2 = 0.f;                // c1 lives in A, c2 in B
    if (tid < 256) {
        (&h1l[0][0][0])[tid] = (f16)0.f;
        (&h2l[0][0][0])[tid] = (f16)0.f;
    }
    __syncthreads();

    const f32x4 z4 = {0.f, 0.f, 0.f, 0.f};

    // x prefetch registers (A only)
    f32x4 xq = z4, xnq = z4;
    if (!isB) xq = *(const f32x4*)&xst[0][qb * 4];

    // ---------------- encoder: 1026 pipelined ticks, 1 barrier each --------
    // tick tau: A computes h1(tau) [tau<1024] AND proj(tau-1)=E2ih@h1(tau-1)
    //           [1<=tau<=1024] reusing the same a0/a1 fragments;
    //           B computes h2(tau-2)=f(proj(tau-2), h2(tau-3)) [tau>=2].
#pragma unroll 1
    for (int tau = 0; tau <= 1025; tau++) {
        if (!isB) {
            if (tau <= 1024) {
                const f16* h1p = h1l[(tau + 1) & 1][ab];   // h1(tau-1)
                f16x8 a0 = *(const f16x8*)(h1p + quad * 8);
                f16x8 a1 = *(const f16x8*)(h1p + 32 + quad * 8);
                if (tau < 1024) {            // L1: h1(tau) = f(h1(tau-1), x(tau))
                    float xt[4];
#pragma unroll
                    for (int g = 0; g < 4; g++)
                        xt[g] = fmaf(xw[g][0], xq.x,
                                fmaf(xw[g][1], xq.y, fmaf(xw[g][2], xq.z, bias1[g])));
                    f32x4 acc[4];
#pragma unroll
                    for (int g = 0; g < 4; g++)
                        acc[g] = MFMA16(a1, E1hh[g][1], MFMA16(a0, E1hh[g][0], z4));
                    float v[4];
#pragma unroll
                    for (int g = 0; g < 4; g++)
                        v[g] = (qb ? acc[g][1] : acc[g][0]) + xt[g];
                    float iv = sig2(v[0]), fv = sig2(v[1]);
                    float gv = fmaf(2.0f, sig2(v[2]), -1.0f), ov = sig2(v[3]);
                    c1 = fv * c1 + iv * gv;
                    if (quad < 2) h1l[tau & 1][quad][u16] = (f16)(ov * tanh2(c1));
                    // prefetch next x (read-only region; off the post-barrier burst)
                    const int tn = (tau + 1 < 1024) ? tau + 1 : 1023;
                    xnq = *(const f32x4*)&xst[tn][qb * 4];
                }
                if (tau >= 1) {              // proj(tau-1) = E2ih @ h1(tau-1)
                    f32x4 ap[4];
#pragma unroll
                    for (int g = 0; g < 4; g++)
                        ap[g] = MFMA16(a1, E2ih[g][1], MFMA16(a0, E2ih[g][0], z4));
                    if (quad < 2) {
                        f32x4 pv;
#pragma unroll
                        for (int g = 0; g < 4; g++)
                            pv[g] = qb ? ap[g][1] : ap[g][0];
                        *(f32x4*)&prj[(tau + 1) & 1][qb][u16][0] = pv;
                    }
                }
            }
        } else {
            if (tau >= 2) {                  // L2: h2(tau-2) = f(proj(tau-2), h2(tau-3))
                const f16* h2p = h2l[(tau + 1) & 1][ab];   // h2(tau-3)
                f32x4 pj = *(const f32x4*)&prj[tau & 1][qb][u16][0];  // proj(tau-2)
                f16x8 b0 = *(const f16x8*)(h2p + quad * 8);
                f16x8 b1 = *(const f16x8*)(h2p + 32 + quad * 8);
                f32x4 accB[4];               // bias via C-init
#pragma unroll
                for (int g = 0; g < 4; g++)
                    accB[g] = MFMA16(b1, E2hh[g][1], MFMA16(b0, E2hh[g][0], bs2[g]));
                float v[4];
#pragma unroll
                for (int g = 0; g < 4; g++)
                    v[g] = pj[g] + (qb ? accB[g][1] : accB[g][0]);
                float iv = sig2(v[0]), fv = sig2(v[1]);
                float gv = fmaf(2.0f, sig2(v[2]), -1.0f), ov = sig2(v[3]);
                c2 = fv * c2 + iv * gv;
                if (quad < 2) h2l[tau & 1][quad][u16] = (f16)(ov * tanh2(c2));
            }
        }
        __syncthreads();
        if (!isB) xq = xnq;
    }
    // h2(1023) in h2l[1025&1 = 1]; c2 in B registers

    // ---------------- decoder weights (group-specialized) -------------------
    f16x8 D1hh[4][2];                        // A
    f16x8 W2s[4][2];                         // B
    float dxw[4][3], db1[4];
    f32x4 db2s[4];                           // B: dec2 bias splat (C-init)
    if (!isB) {
#pragma unroll
        for (int g = 0; g < 4; g++) {
            const float s = (g == 2) ? (-2.0f * LOG2E) : (-LOG2E);
            const int n = g * 64 + u16;
#pragma unroll
            for (int c = 0; c < 2; c++)
                D1hh[g][c] = ldfrag(d1hh, n, c * 32 + quad * 8, s);
            dxw[g][0] = s * d1ih[n * 3 + 0];
            dxw[g][1] = s * d1ih[n * 3 + 1];
            dxw[g][2] = s * d1ih[n * 3 + 2];
            db1[g] = s * d1b[n];
        }
    } else {
#pragma unroll
        for (int g = 0; g < 4; g++) {
            const float s = (g == 2) ? (-2.0f * LOG2E) : (-LOG2E);
            const int n = g * 64 + u16;
#pragma unroll
            for (int c = 0; c < 2; c++) {
                const int k0 = c * 32 + quad * 8;
                const float* pa = d2ih + (size_t)n * 64 + k0;
                const float* pb = d2hh + (size_t)n * 64 + k0;
                f16x8 r2;
#pragma unroll
                for (int j = 0; j < 8; j++) r2[j] = (f16)(s * (pa[j] + pb[j]));
                W2s[g][c] = r2;
            }
            float bv = s * d2b[n];
            db2s[g] = (f32x4){bv, bv, bv, bv};
        }
        // seed c2buf with encoder final c2 (A reads it at t=0)
        if (quad < 2) c2buf[quad][u16] = c2;
    }
    // FC: register B-fragments of fcW^T (waves 6-7), B[k][n]=fcW[n][k], n=c15
    f16x8 FW0 = {}, FW1 = {};
    float fb = 0.f;
    if (wv >= 6 && c15 < 3) {
#pragma unroll
        for (int j = 0; j < 8; j++) {
            FW0[j] = (f16)fcW[c15 * 64 + quad * 8 + j];
            FW1[j] = (f16)fcW[c15 * 64 + 32 + quad * 8 + j];
        }
        fb = fcb[c15];
    }
    __syncthreads();

    // trg prefetch registers (A only)
    f32x4 tq = z4, tnq = z4;
    if (!isB) tq = *(const f32x4*)&tst[0][qb * 4];

    // ---------------- decoder: 511 steps, 2 barriers each -------------------
    // (serial chain c2->dec1->c1->dec2 has zero slack; 2 handoffs/step is
    //  structural -- each cell's output feeds the next cell cross-group)
    // NOTE: encoder leaves h2(1023) in h2l[1], so A reads h2l[w] (=(t+1)&1)
    // and B writes h2l[r] (=t&1) -- parity flipped vs the original round-0.
#pragma unroll 1
    for (int t = 0; t < 511; t++) {
        const int r = t & 1, w = r ^ 1;
        if (!isB) {
            // ---- dec1 (waves 0-3) ----
            const f16* hp = h2l[w][ab];      // h2d(t-1)
            f16x8 a0 = *(const f16x8*)(hp + quad * 8);
            f16x8 a1 = *(const f16x8*)(hp + 32 + quad * 8);
            float cdin = c2buf[qb][u16];
            float xt[4];
#pragma unroll
            for (int g = 0; g < 4; g++)
                xt[g] = fmaf(dxw[g][0], tq.x,
                        fmaf(dxw[g][1], tq.y, fmaf(dxw[g][2], tq.z, db1[g])));
            f32x4 acc[4];
#pragma unroll
            for (int g = 0; g < 4; g++)
                acc[g] = MFMA16(a1, D1hh[g][1], MFMA16(a0, D1hh[g][0], z4));
            float v[4];
#pragma unroll
            for (int g = 0; g < 4; g++)
                v[g] = (qb ? acc[g][1] : acc[g][0]) + xt[g];
            float iv = sig2(v[0]), fv = sig2(v[1]);
            float gv = fmaf(2.0f, sig2(v[2]), -1.0f), ov = sig2(v[3]);
            float c1d = fv * cdin + iv * gv;
            if (quad < 2) {
                h1l[w][quad][u16] = (f16)(ov * tanh2(c1d));
                c1buf[quad][u16]  = c1d;
            }
            const int tn = (t + 1 < 511) ? t + 1 : 510;
            tnq = *(const f32x4*)&tst[tn][qb * 4];
        } else if (wv >= 6 && t > 0 && (t & 15) == 0) {
            // ---- batched FC for steps t-16..t-1 (2 MFMAs), overlapped ----
            const int bsel = wv - 6;
            const f16* rp = &ring[bsel][0][0];
            f16x8 fa0 = *(const f16x8*)(rp + c15 * 72 + quad * 8);
            f16x8 fa1 = *(const f16x8*)(rp + c15 * 72 + 32 + quad * 8);
            f32x4 acc = MFMA16(fa1, FW1, MFMA16(fa0, FW0, z4));
            if (c15 < 3) {
                float* ob = out + (((size_t)(2 * bp + bsel) * 512 + (t - 15)) * 3) + c15;
#pragma unroll
                for (int rg = 0; rg < 4; rg++)
                    ob[(quad * 4 + rg) * 3] = acc[rg] + fb;
            }
        }
        __syncthreads();   // B1: h1d, c1d visible
        if (!isB) tq = tnq;

        if (isB) {
            // ---- dec2 (waves 4-7): x = h = h1d ----
            const f16* np = h1l[w][ab];
            f16x8 m0 = *(const f16x8*)(np + quad * 8);
            f16x8 m1 = *(const f16x8*)(np + 32 + quad * 8);
            float c1in = c1buf[qb][u16];
            f32x4 acc[4];
#pragma unroll
            for (int g = 0; g < 4; g++)
                acc[g] = MFMA16(m1, W2s[g][1], MFMA16(m0, W2s[g][0], db2s[g]));
            float v[4];
#pragma unroll
            for (int g = 0; g < 4; g++)
                v[g] = (qb ? acc[g][1] : acc[g][0]);
            float i2 = sig2(v[0]), f2 = sig2(v[1]);
            float g2 = fmaf(2.0f, sig2(v[2]), -1.0f), o2 = sig2(v[3]);
            float c2d = f2 * c1in + i2 * g2;
            if (quad < 2) {
                f16 hh = (f16)(o2 * tanh2(c2d));
                h2l[r][quad][u16] = hh;      // parity-flipped (see note above)
                c2buf[quad][u16]  = c2d;
                ring[quad][t & 15][u16] = hh;   // FC history
            }
        }
        __syncthreads();   // B2: hD(t), c2d visible
    }

    // drain: FC for steps 496..510 (ring slots 0..14) -> out rows 497..511
    if (wv >= 6) {
        const int bsel = wv - 6;
        const f16* rp = &ring[bsel][0][0];
        f16x8 fa0 = *(const f16x8*)(rp + c15 * 72 + quad * 8);
        f16x8 fa1 = *(const f16x8*)(rp + c15 * 72 + 32 + quad * 8);
        f32x4 acc = MFMA16(fa1, FW1, MFMA16(fa0, FW0, z4));
        if (c15 < 3) {
            float* ob = out + (((size_t)(2 * bp + bsel) * 512 + 497) * 3) + c15;
#pragma unroll
            for (int rg = 0; rg < 4; rg++) {
                int step = quad * 4 + rg;
                if (step < 15) ob[step * 3] = acc[rg] + fb;
            }
        }
    }
}

extern "C" void kernel_launch(void* const* d_in, const int* in_sizes, int n_in,
                              void* d_out, int out_size, void* d_ws, size_t ws_size,
                              hipStream_t stream)
{
    const float* src   = (const float*)d_in[0];
    const float* trg   = (const float*)d_in[1];
    const float* e1ih  = (const float*)d_in[2];
    const float* e1hh  = (const float*)d_in[3];
    const float* e1b   = (const float*)d_in[4];
    const float* e2ih  = (const float*)d_in[5];
    const float* e2hh  = (const float*)d_in[6];
    const float* e2b   = (const float*)d_in[7];
    const float* dd1ih = (const float*)d_in[8];
    const float* dd1hh = (const float*)d_in[9];
    const float* dd1b  = (const float*)d_in[10];
    const float* dd2ih = (const float*)d_in[11];
    const float* dd2hh = (const float*)d_in[12];
    const float* dd2b  = (const float*)d_in[13];
    const float* fcW   = (const float*)d_in[14];
    const float* fcb   = (const float*)d_in[15];
    float* out = (float*)d_out;

    // outputs[:, 0, :] stays 0; decoder fills t >= 1
    hipMemsetAsync(d_out, 0, (size_t)out_size * sizeof(float), stream);

    seq2seq_kernel<<<256, 512, 0, stream>>>(src, trg,
                                            e1ih, e1hh, e1b, e2ih, e2hh, e2b,
                                            dd1ih, dd1hh, dd1b, dd2ih, dd2hh, dd2b,
                                            fcW, fcb, out);
}